// Round 1
// baseline (1392.068 us; speedup 1.0000x reference)
//
#include <hip/hip_runtime.h>
#include <hip/hip_bf16.h>

typedef __attribute__((ext_vector_type(8))) __bf16 bf16x8;
typedef __attribute__((ext_vector_type(4))) float f32x4;

#define DEVI __device__ __forceinline__

static constexpr int NVOX = 262144;

DEVI unsigned short f2b_rne(float f) {
    unsigned int u = __float_as_uint(f);
    u = (u + 0x7fffu + ((u >> 16) & 1u)) >> 16;
    return (unsigned short)u;
}
DEVI float b2f(unsigned short h) {
    return __uint_as_float(((unsigned int)h) << 16);
}
DEVI bf16x8 ld8(const unsigned short* p) { return *reinterpret_cast<const bf16x8*>(p); }
DEVI f32x4 mfma16(bf16x8 a, bf16x8 b, f32x4 c) {
    return __builtin_amdgcn_mfma_f32_16x16x32_bf16(a, b, c, 0, 0, 0);
}

DEVI void stage16(const unsigned short* __restrict__ src, unsigned short* dst,
                  int n16, int tid, int nthr) {
    const float4* s = reinterpret_cast<const float4*>(src);
    float4* d = reinterpret_cast<float4*>(dst);
    for (int c = tid; c < n16; c += nthr) d[c] = s[c];
}

// ---------------- conversion kernels ----------------

__global__ void f2b_kernel(const float* __restrict__ src, unsigned short* __restrict__ dst) {
    const size_t i = (size_t)(blockIdx.x * 256 + threadIdx.x) * 8;
    const float4 a = *reinterpret_cast<const float4*>(src + i);
    const float4 b = *reinterpret_cast<const float4*>(src + i + 4);
    union { unsigned short h[8]; uint4 v; } o;
    o.h[0] = f2b_rne(a.x); o.h[1] = f2b_rne(a.y); o.h[2] = f2b_rne(a.z); o.h[3] = f2b_rne(a.w);
    o.h[4] = f2b_rne(b.x); o.h[5] = f2b_rne(b.y); o.h[6] = f2b_rne(b.z); o.h[7] = f2b_rne(b.w);
    *reinterpret_cast<uint4*>(dst + i) = o.v;
}

// Repack W [K][Cin][Cout] fp32 -> bf16 fragment-order blobs:
// blob = (k*KC + kc)*NT + nt ; within blob: lane (0..63), j (0..7)
// element = W[k][kc*32 + (lane>>4)*8 + j][nt*16 + (lane&15)]
__global__ void wconv_kernel(const float* __restrict__ src, unsigned short* __restrict__ dst,
                             int K, int Cin, int Cout) {
    const int KC = Cin >> 5, NT = Cout >> 4;
    const int total = K * KC * NT * 512;
    src += (size_t)blockIdx.y * K * Cin * Cout;
    dst += (size_t)blockIdx.y * total;
    for (int e = blockIdx.x * 256 + threadIdx.x; e < total; e += gridDim.x * 256) {
        const int j = e & 7;
        const int ln = (e >> 3) & 63;
        const int blob = e >> 9;
        const int nt = blob % NT;
        const int t = blob / NT;
        const int kc = t % KC;
        const int k = t / KC;
        const int cin = kc * 32 + (ln >> 4) * 8 + j;
        const int cout = nt * 16 + (ln & 15);
        dst[e] = f2b_rne(src[((size_t)k * Cin + cin) * Cout + cout]);
    }
}

// ---------------- main conv kernels ----------------
// Block: 1024 threads = 16 waves; wave owns 32 voxels (2 M-fragments of 16).
// A-frag: lane holds A[row=lane&15][k=(lane>>4)*8+j] ; B-frag from LDS blob at lane*16B.
// C/D: row=(lane>>4)*4+reg, col=lane&15  (m89-verified layout).

template<bool RELU, bool OUTF32>
__global__ __launch_bounds__(1024)
void conv_full_kernel(const unsigned short* __restrict__ in,
                      const int* __restrict__ nbr,
                      const unsigned short* __restrict__ wf,
                      void* __restrict__ outv)
{
    __shared__ unsigned short wlds[14 * 8 * 512];   // 14 k-slots x 8 blobs
    const int tid = threadIdx.x;
    const int lane = tid & 63, wave = tid >> 6;
    const int lrow = lane & 15, lkg = lane >> 4;
    const int vb = blockIdx.x * 512 + wave * 32;

    const f32x4 FZ = {0.f, 0.f, 0.f, 0.f};
    f32x4 acc[2][4];
#pragma unroll
    for (int m = 0; m < 2; ++m)
#pragma unroll
        for (int nt = 0; nt < 4; ++nt) acc[m][nt] = FZ;

#pragma unroll 1
    for (int stage = 0; stage < 2; ++stage) {
        const int k0 = stage * 14;
        const int nk = stage ? 13 : 14;
        __syncthreads();
        stage16(wf + (size_t)k0 * 8 * 512, wlds, nk * 8 * 64, tid, 1024);
        __syncthreads();
#pragma unroll 1
        for (int kk = 0; kk < nk; ++kk) {
            const int k = k0 + kk;
            const int idx0 = nbr[(vb + lrow) * 27 + k];
            const int idx1 = nbr[(vb + 16 + lrow) * 27 + k];
            const unsigned short* a0 = in + (size_t)idx0 * 64;
            const unsigned short* a1 = in + (size_t)idx1 * 64;
            const unsigned short* bl = wlds + kk * 8 * 512 + lane * 8;
#pragma unroll
            for (int kc = 0; kc < 2; ++kc) {
                const bf16x8 af0 = ld8(a0 + kc * 32 + lkg * 8);
                const bf16x8 af1 = ld8(a1 + kc * 32 + lkg * 8);
#pragma unroll
                for (int nt = 0; nt < 4; ++nt) {
                    const bf16x8 bf = ld8(bl + (kc * 4 + nt) * 512);
                    acc[0][nt] = mfma16(af0, bf, acc[0][nt]);
                    acc[1][nt] = mfma16(af1, bf, acc[1][nt]);
                }
            }
        }
    }

#pragma unroll
    for (int m = 0; m < 2; ++m)
#pragma unroll
        for (int nt = 0; nt < 4; ++nt)
#pragma unroll
            for (int r = 0; r < 4; ++r) {
                const int v = vb + m * 16 + lkg * 4 + r;
                float val = acc[m][nt][r];
                if (RELU) val = fmaxf(val, 0.f);
                if (OUTF32)
                    reinterpret_cast<float*>(outv)[(size_t)v * 64 + nt * 16 + lrow] = val;
                else
                    reinterpret_cast<unsigned short*>(outv)[(size_t)v * 64 + nt * 16 + lrow] = f2b_rne(val);
            }
}

// K_A: u[:, :32] = relu(conv27(h, b00)); u[:, 32:] = relu(h @ b10)
__global__ __launch_bounds__(1024)
void kernel_A(const unsigned short* __restrict__ h,
              const int* __restrict__ nbr,
              const unsigned short* __restrict__ b00f,
              const unsigned short* __restrict__ b10f,
              unsigned short* __restrict__ u)
{
    __shared__ unsigned short wlds[(27 * 4 + 4) * 512];
    const int tid = threadIdx.x;
    const int lane = tid & 63, wave = tid >> 6;
    const int lrow = lane & 15, lkg = lane >> 4;
    const int vb = blockIdx.x * 512 + wave * 32;

    stage16(b00f, wlds, 27 * 4 * 64, tid, 1024);
    stage16(b10f, wlds + 27 * 4 * 512, 4 * 64, tid, 1024);
    __syncthreads();

    const f32x4 FZ = {0.f, 0.f, 0.f, 0.f};
    f32x4 acc0[2][2], acc1[2][2];
#pragma unroll
    for (int m = 0; m < 2; ++m)
#pragma unroll
        for (int nt = 0; nt < 2; ++nt) { acc0[m][nt] = FZ; acc1[m][nt] = FZ; }

#pragma unroll 1
    for (int k = 0; k < 27; ++k) {
        const int idx0 = nbr[(vb + lrow) * 27 + k];
        const int idx1 = nbr[(vb + 16 + lrow) * 27 + k];
        const unsigned short* a0 = h + (size_t)idx0 * 64;
        const unsigned short* a1 = h + (size_t)idx1 * 64;
        const unsigned short* bl = wlds + k * 4 * 512 + lane * 8;
#pragma unroll
        for (int kc = 0; kc < 2; ++kc) {
            const bf16x8 af0 = ld8(a0 + kc * 32 + lkg * 8);
            const bf16x8 af1 = ld8(a1 + kc * 32 + lkg * 8);
#pragma unroll
            for (int nt = 0; nt < 2; ++nt) {
                const bf16x8 bf = ld8(bl + (kc * 2 + nt) * 512);
                acc0[0][nt] = mfma16(af0, bf, acc0[0][nt]);
                acc0[1][nt] = mfma16(af1, bf, acc0[1][nt]);
            }
        }
    }
    {   // t1 = h @ b10 (own row)
        const unsigned short* bl = wlds + 27 * 4 * 512 + lane * 8;
#pragma unroll
        for (int m = 0; m < 2; ++m) {
            const unsigned short* ar = h + (size_t)(vb + m * 16 + lrow) * 64;
#pragma unroll
            for (int kc = 0; kc < 2; ++kc) {
                const bf16x8 af = ld8(ar + kc * 32 + lkg * 8);
#pragma unroll
                for (int nt = 0; nt < 2; ++nt) {
                    const bf16x8 bf = ld8(bl + (kc * 2 + nt) * 512);
                    acc1[m][nt] = mfma16(af, bf, acc1[m][nt]);
                }
            }
        }
    }
#pragma unroll
    for (int m = 0; m < 2; ++m)
#pragma unroll
        for (int nt = 0; nt < 2; ++nt)
#pragma unroll
            for (int r = 0; r < 4; ++r) {
                const int v = vb + m * 16 + lkg * 4 + r;
                u[(size_t)v * 64 + nt * 16 + lrow] = f2b_rne(fmaxf(acc0[m][nt][r], 0.f));
                u[(size_t)v * 64 + 32 + nt * 16 + lrow] = f2b_rne(fmaxf(acc1[m][nt][r], 0.f));
            }
}

// K_B: out0 = conv27(u_lo, b01); t2 = relu(conv27(u_hi, b11)); out1 = t2 @ b12;
// hout = [out0|out1] + hres (+ xres if non-null)
__global__ __launch_bounds__(1024)
void kernel_B(const unsigned short* __restrict__ u,
              const int* __restrict__ nbr,
              const unsigned short* __restrict__ b01f,
              const unsigned short* __restrict__ b11f,
              const unsigned short* __restrict__ b12f,
              const unsigned short* __restrict__ hres,
              const unsigned short* __restrict__ xres,
              unsigned short* __restrict__ hout)
{
    __shared__ unsigned short wlds[110 * 512];
    __shared__ unsigned short t2lds[16][512];
    const int tid = threadIdx.x;
    const int lane = tid & 63, wave = tid >> 6;
    const int lrow = lane & 15, lkg = lane >> 4;
    const int vb = blockIdx.x * 512 + wave * 32;

    stage16(b01f, wlds, 54 * 64, tid, 1024);
    stage16(b11f, wlds + 54 * 512, 54 * 64, tid, 1024);
    stage16(b12f, wlds + 108 * 512, 2 * 64, tid, 1024);
    __syncthreads();

    const f32x4 FZ = {0.f, 0.f, 0.f, 0.f};
    f32x4 acc0[2][2], acc1[2][2];
#pragma unroll
    for (int m = 0; m < 2; ++m)
#pragma unroll
        for (int nt = 0; nt < 2; ++nt) { acc0[m][nt] = FZ; acc1[m][nt] = FZ; }

#pragma unroll 1
    for (int k = 0; k < 27; ++k) {
        const int idx0 = nbr[(vb + lrow) * 27 + k];
        const int idx1 = nbr[(vb + 16 + lrow) * 27 + k];
        const unsigned short* a0 = u + (size_t)idx0 * 64;
        const unsigned short* a1 = u + (size_t)idx1 * 64;
        const bf16x8 af00 = ld8(a0 + lkg * 8);
        const bf16x8 af01 = ld8(a0 + 32 + lkg * 8);
        const bf16x8 af10 = ld8(a1 + lkg * 8);
        const bf16x8 af11 = ld8(a1 + 32 + lkg * 8);
        const unsigned short* bl = wlds + lane * 8;
#pragma unroll
        for (int nt = 0; nt < 2; ++nt) {
            const bf16x8 w01 = ld8(bl + (k * 2 + nt) * 512);
            const bf16x8 w11 = ld8(bl + (54 + k * 2 + nt) * 512);
            acc0[0][nt] = mfma16(af00, w01, acc0[0][nt]);
            acc0[1][nt] = mfma16(af10, w01, acc0[1][nt]);
            acc1[0][nt] = mfma16(af01, w11, acc1[0][nt]);
            acc1[1][nt] = mfma16(af11, w11, acc1[1][nt]);
        }
    }

    // out1 = relu(acc1) @ b12 via per-wave LDS transpose (XOR granule swizzle)
    f32x4 out1[2][2];
    char* tb = reinterpret_cast<char*>(&t2lds[wave][0]);
#pragma unroll
    for (int m = 0; m < 2; ++m) {
#pragma unroll
        for (int nt = 0; nt < 2; ++nt)
#pragma unroll
            for (int r = 0; r < 4; ++r) {
                const int row = lkg * 4 + r;
                const int byte = (nt * 16 + lrow) * 2;
                const int off = row * 64 + (((byte >> 4) ^ (row & 3)) << 4) + (byte & 15);
                *reinterpret_cast<unsigned short*>(tb + off) = f2b_rne(fmaxf(acc1[m][nt][r], 0.f));
            }
        __syncthreads();
        const int roff = lrow * 64 + ((lkg ^ (lrow & 3)) << 4);
        const bf16x8 af2 = *reinterpret_cast<const bf16x8*>(tb + roff);
#pragma unroll
        for (int nt = 0; nt < 2; ++nt) {
            const bf16x8 w12 = ld8(wlds + (108 + nt) * 512 + lane * 8);
            out1[m][nt] = mfma16(af2, w12, FZ);
        }
        __syncthreads();   // protects t2lds reuse (read m before write m+1)
    }

#pragma unroll
    for (int m = 0; m < 2; ++m)
#pragma unroll
        for (int nt = 0; nt < 2; ++nt)
#pragma unroll
            for (int r = 0; r < 4; ++r) {
                const int v = vb + m * 16 + lkg * 4 + r;
                const int c0 = nt * 16 + lrow;
                const int c1 = 32 + c0;
                float r0 = acc0[m][nt][r] + b2f(hres[(size_t)v * 64 + c0]);
                float r1 = out1[m][nt][r] + b2f(hres[(size_t)v * 64 + c1]);
                if (xres) {
                    r0 += b2f(xres[(size_t)v * 64 + c0]);
                    r1 += b2f(xres[(size_t)v * 64 + c1]);
                }
                hout[(size_t)v * 64 + c0] = f2b_rne(r0);
                hout[(size_t)v * 64 + c1] = f2b_rne(r1);
            }
}

// ---------------- host ----------------

extern "C" void kernel_launch(void* const* d_in, const int* in_sizes, int n_in,
                              void* d_out, int out_size, void* d_ws, size_t ws_size,
                              hipStream_t stream)
{
    const float* feats = (const float*)d_in[0];
    const int*   nbr   = (const int*)d_in[1];
    const float* w1    = (const float*)d_in[2];
    const float* w2    = (const float*)d_in[3];
    const float* b00   = (const float*)d_in[4];
    const float* b01   = (const float*)d_in[5];
    const float* b10   = (const float*)d_in[6];
    const float* b11   = (const float*)d_in[7];
    const float* b12   = (const float*)d_in[8];

    const size_t NC = (size_t)NVOX * 64;               // 16777216 elements
    unsigned short* xbuf = (unsigned short*)d_ws;      // x = relu(conv1)
    unsigned short* hbuf = xbuf + NC;                  // residual stream h
    unsigned short* wbuf = hbuf + NC;                  // bf16 frag-order weights
    if (ws_size < (2 * NC + 562176) * sizeof(unsigned short)) return;

    // d_out (fp32, 64MB) doubles as scratch for fbuf+ubuf until the final conv overwrites it
    unsigned short* fbuf = (unsigned short*)d_out;     // feats bf16
    unsigned short* ubuf = fbuf + NC;                  // u = [t0|t1]

    const size_t OFF_W1 = 0, OFF_W2 = 110592, OFF_B00 = 221184, OFF_B01 = 387072,
                 OFF_B10 = 470016, OFF_B11 = 476160, OFF_B12 = 559104;

    f2b_kernel<<<8192, 256, 0, stream>>>(feats, fbuf);
    wconv_kernel<<<dim3(432, 1), 256, 0, stream>>>(w1, wbuf + OFF_W1, 27, 64, 64);
    wconv_kernel<<<dim3(432, 1), 256, 0, stream>>>(w2, wbuf + OFF_W2, 27, 64, 64);
    wconv_kernel<<<dim3(216, 3), 256, 0, stream>>>(b00, wbuf + OFF_B00, 27, 64, 32);
    wconv_kernel<<<dim3(108, 3), 256, 0, stream>>>(b01, wbuf + OFF_B01, 27, 32, 32);
    wconv_kernel<<<dim3(8, 3),   256, 0, stream>>>(b10, wbuf + OFF_B10, 1, 64, 32);
    wconv_kernel<<<dim3(108, 3), 256, 0, stream>>>(b11, wbuf + OFF_B11, 27, 32, 32);
    wconv_kernel<<<dim3(4, 3),   256, 0, stream>>>(b12, wbuf + OFF_B12, 1, 32, 32);

    // x = relu(conv27(feats, w1))
    conv_full_kernel<true, false><<<512, 1024, 0, stream>>>(fbuf, nbr, wbuf + OFF_W1, xbuf);

    for (int i = 0; i < 3; ++i) {
        kernel_A<<<512, 1024, 0, stream>>>(i ? hbuf : xbuf, nbr,
                                           wbuf + OFF_B00 + (size_t)i * 55296,
                                           wbuf + OFF_B10 + (size_t)i * 2048, ubuf);
        kernel_B<<<512, 1024, 0, stream>>>(ubuf, nbr,
                                           wbuf + OFF_B01 + (size_t)i * 27648,
                                           wbuf + OFF_B11 + (size_t)i * 27648,
                                           wbuf + OFF_B12 + (size_t)i * 1024,
                                           i ? hbuf : xbuf,
                                           (i == 2) ? xbuf : (const unsigned short*)nullptr,
                                           hbuf);
    }

    // final: d_out = conv27(h3 + x, w2)  (fp32 out)
    conv_full_kernel<false, true><<<512, 1024, 0, stream>>>(hbuf, nbr, wbuf + OFF_W2, d_out);
}

// Round 2
// 1174.317 us; speedup vs baseline: 1.1854x; 1.1854x over previous
//
#include <hip/hip_runtime.h>
#include <hip/hip_bf16.h>

typedef __attribute__((ext_vector_type(8))) __bf16 bf16x8;
typedef __attribute__((ext_vector_type(4))) float f32x4;

#define DEVI __device__ __forceinline__

static constexpr int NVOX = 262144;

DEVI unsigned short f2b_rne(float f) {
    unsigned int u = __float_as_uint(f);
    u = (u + 0x7fffu + ((u >> 16) & 1u)) >> 16;
    return (unsigned short)u;
}
DEVI float b2f(unsigned short h) {
    return __uint_as_float(((unsigned int)h) << 16);
}
DEVI bf16x8 ld8(const unsigned short* p) { return *reinterpret_cast<const bf16x8*>(p); }
DEVI f32x4 mfma16(bf16x8 a, bf16x8 b, f32x4 c) {
    return __builtin_amdgcn_mfma_f32_16x16x32_bf16(a, b, c, 0, 0, 0);
}

DEVI void stage16(const unsigned short* __restrict__ src, unsigned short* dst,
                  int n16, int tid, int nthr) {
    const float4* s = reinterpret_cast<const float4*>(src);
    float4* d = reinterpret_cast<float4*>(dst);
    for (int c = tid; c < n16; c += nthr) d[c] = s[c];
}

// ---------------- conversion kernels ----------------

__global__ void f2b_kernel(const float* __restrict__ src, unsigned short* __restrict__ dst) {
    const size_t i = (size_t)(blockIdx.x * 256 + threadIdx.x) * 8;
    const float4 a = *reinterpret_cast<const float4*>(src + i);
    const float4 b = *reinterpret_cast<const float4*>(src + i + 4);
    union { unsigned short h[8]; uint4 v; } o;
    o.h[0] = f2b_rne(a.x); o.h[1] = f2b_rne(a.y); o.h[2] = f2b_rne(a.z); o.h[3] = f2b_rne(a.w);
    o.h[4] = f2b_rne(b.x); o.h[5] = f2b_rne(b.y); o.h[6] = f2b_rne(b.z); o.h[7] = f2b_rne(b.w);
    *reinterpret_cast<uint4*>(dst + i) = o.v;
}

// Repack W [K][Cin][Cout] fp32 -> bf16 fragment-order blobs:
// blob = (k*KC + kc)*NT + nt ; within blob: lane (0..63), j (0..7)
// element = W[k][kc*32 + (lane>>4)*8 + j][nt*16 + (lane&15)]
__global__ void wconv_kernel(const float* __restrict__ src, unsigned short* __restrict__ dst,
                             int K, int Cin, int Cout) {
    const int KC = Cin >> 5, NT = Cout >> 4;
    const int total = K * KC * NT * 512;
    src += (size_t)blockIdx.y * K * Cin * Cout;
    dst += (size_t)blockIdx.y * total;
    for (int e = blockIdx.x * 256 + threadIdx.x; e < total; e += gridDim.x * 256) {
        const int j = e & 7;
        const int ln = (e >> 3) & 63;
        const int blob = e >> 9;
        const int nt = blob % NT;
        const int t = blob / NT;
        const int kc = t % KC;
        const int k = t / KC;
        const int cin = kc * 32 + (ln >> 4) * 8 + j;
        const int cout = nt * 16 + (ln & 15);
        dst[e] = f2b_rne(src[((size_t)k * Cin + cin) * Cout + cout]);
    }
}

// ---------------- main conv kernels ----------------
// Block: 1024 threads = 16 waves; wave owns 32 voxels (2 M-fragments of 16).
// A-frag: lane holds A[row=lane&15][k=(lane>>4)*8+j] ; B-frag from LDS blob at lane*16B.
// C/D: row=(lane>>4)*4+reg, col=lane&15.
// Software pipeline: idx ring ID=6 (issue 6 iters ahead), gather ring 3 slots
// (issue 2 iters ahead, consume slot t%3, write slot (t+2)%3 -> WAR-free).

template<bool RELU, bool OUTF32>
__global__ __launch_bounds__(1024)
void conv_full_kernel(const unsigned short* __restrict__ in,
                      const int* __restrict__ nbr,
                      const unsigned short* __restrict__ wf,
                      void* __restrict__ outv)
{
    __shared__ unsigned short wlds[14 * 8 * 512];   // 14 k-slots x 8 blobs
    const int tid = threadIdx.x;
    const int lane = tid & 63, wave = tid >> 6;
    const int lrow = lane & 15, lkg = lane >> 4;
    const int vb = blockIdx.x * 512 + wave * 32;

    constexpr int ID = 6;   // idx issue-ahead
    constexpr int GS = 3;   // gather ring slots (issue-ahead 2)

    const int* nrow0 = nbr + (size_t)(vb + lrow) * 27;
    const int* nrow1 = nbr + (size_t)(vb + 16 + lrow) * 27;

    int i0[ID], i1[ID];
    bf16x8 ga[GS][2][2];    // [slot][m][kc]

    // prologue: idx for t=0..5, gathers for t=0,1 (issued before staging so
    // they overlap the weight-stage latency)
#pragma unroll
    for (int t = 0; t < ID; ++t) { i0[t] = nrow0[t]; i1[t] = nrow1[t]; }
#pragma unroll
    for (int t = 0; t < 2; ++t) {
        const unsigned short* a0 = in + (size_t)i0[t] * 64 + lkg * 8;
        const unsigned short* a1 = in + (size_t)i1[t] * 64 + lkg * 8;
        ga[t][0][0] = ld8(a0); ga[t][0][1] = ld8(a0 + 32);
        ga[t][1][0] = ld8(a1); ga[t][1][1] = ld8(a1 + 32);
    }

    stage16(wf, wlds, 14 * 8 * 64, tid, 1024);

    const f32x4 FZ = {0.f, 0.f, 0.f, 0.f};
    f32x4 acc[2][4];
#pragma unroll
    for (int m = 0; m < 2; ++m)
#pragma unroll
        for (int nt = 0; nt < 4; ++nt) acc[m][nt] = FZ;

    __syncthreads();

#pragma unroll
    for (int t = 0; t < 27; ++t) {
        if (t == 14) {
            __syncthreads();
            stage16(wf + (size_t)14 * 8 * 512, wlds, 13 * 8 * 64, tid, 1024);
            __syncthreads();
        }
        // issue idx loads for t+ID
        if (t + ID < 27) {
            i0[t % ID] = nrow0[t + ID];
            i1[t % ID] = nrow1[t + ID];
        }
        // issue gathers for t+2 into slot (t+2)%GS
        if (t + 2 < 27) {
            const int u = t + 2, s = u % GS;
            const unsigned short* a0 = in + (size_t)i0[u % ID] * 64 + lkg * 8;
            const unsigned short* a1 = in + (size_t)i1[u % ID] * 64 + lkg * 8;
            ga[s][0][0] = ld8(a0); ga[s][0][1] = ld8(a0 + 32);
            ga[s][1][0] = ld8(a1); ga[s][1][1] = ld8(a1 + 32);
        }
        // compute iteration t
        const int kk = (t < 14) ? t : t - 14;
        const unsigned short* bl = wlds + kk * 8 * 512 + lane * 8;
        const int s = t % GS;
#pragma unroll
        for (int kc = 0; kc < 2; ++kc)
#pragma unroll
            for (int nt = 0; nt < 4; ++nt) {
                const bf16x8 bf = ld8(bl + (kc * 4 + nt) * 512);
                acc[0][nt] = mfma16(ga[s][0][kc], bf, acc[0][nt]);
                acc[1][nt] = mfma16(ga[s][1][kc], bf, acc[1][nt]);
            }
    }

#pragma unroll
    for (int m = 0; m < 2; ++m)
#pragma unroll
        for (int nt = 0; nt < 4; ++nt)
#pragma unroll
            for (int r = 0; r < 4; ++r) {
                const int v = vb + m * 16 + lkg * 4 + r;
                float val = acc[m][nt][r];
                if (RELU) val = fmaxf(val, 0.f);
                if (OUTF32)
                    reinterpret_cast<float*>(outv)[(size_t)v * 64 + nt * 16 + lrow] = val;
                else
                    reinterpret_cast<unsigned short*>(outv)[(size_t)v * 64 + nt * 16 + lrow] = f2b_rne(val);
            }
}

// K_A: u[:, :32] = relu(conv27(h, b00)); u[:, 32:] = relu(h @ b10)
__global__ __launch_bounds__(1024)
void kernel_A(const unsigned short* __restrict__ h,
              const int* __restrict__ nbr,
              const unsigned short* __restrict__ b00f,
              const unsigned short* __restrict__ b10f,
              unsigned short* __restrict__ u)
{
    __shared__ unsigned short wlds[(27 * 4 + 4) * 512];
    const int tid = threadIdx.x;
    const int lane = tid & 63, wave = tid >> 6;
    const int lrow = lane & 15, lkg = lane >> 4;
    const int vb = blockIdx.x * 512 + wave * 32;

    constexpr int ID = 6;
    constexpr int GS = 3;

    const int* nrow0 = nbr + (size_t)(vb + lrow) * 27;
    const int* nrow1 = nbr + (size_t)(vb + 16 + lrow) * 27;

    int i0[ID], i1[ID];
    bf16x8 ga[GS][2][2];

#pragma unroll
    for (int t = 0; t < ID; ++t) { i0[t] = nrow0[t]; i1[t] = nrow1[t]; }
#pragma unroll
    for (int t = 0; t < 2; ++t) {
        const unsigned short* a0 = h + (size_t)i0[t] * 64 + lkg * 8;
        const unsigned short* a1 = h + (size_t)i1[t] * 64 + lkg * 8;
        ga[t][0][0] = ld8(a0); ga[t][0][1] = ld8(a0 + 32);
        ga[t][1][0] = ld8(a1); ga[t][1][1] = ld8(a1 + 32);
    }

    stage16(b00f, wlds, 27 * 4 * 64, tid, 1024);
    stage16(b10f, wlds + 27 * 4 * 512, 4 * 64, tid, 1024);

    const f32x4 FZ = {0.f, 0.f, 0.f, 0.f};
    f32x4 acc0[2][2], acc1[2][2];
#pragma unroll
    for (int m = 0; m < 2; ++m)
#pragma unroll
        for (int nt = 0; nt < 2; ++nt) { acc0[m][nt] = FZ; acc1[m][nt] = FZ; }

    __syncthreads();

#pragma unroll
    for (int t = 0; t < 27; ++t) {
        if (t + ID < 27) {
            i0[t % ID] = nrow0[t + ID];
            i1[t % ID] = nrow1[t + ID];
        }
        if (t + 2 < 27) {
            const int u2 = t + 2, s = u2 % GS;
            const unsigned short* a0 = h + (size_t)i0[u2 % ID] * 64 + lkg * 8;
            const unsigned short* a1 = h + (size_t)i1[u2 % ID] * 64 + lkg * 8;
            ga[s][0][0] = ld8(a0); ga[s][0][1] = ld8(a0 + 32);
            ga[s][1][0] = ld8(a1); ga[s][1][1] = ld8(a1 + 32);
        }
        const unsigned short* bl = wlds + t * 4 * 512 + lane * 8;
        const int s = t % GS;
#pragma unroll
        for (int kc = 0; kc < 2; ++kc)
#pragma unroll
            for (int nt = 0; nt < 2; ++nt) {
                const bf16x8 bf = ld8(bl + (kc * 2 + nt) * 512);
                acc0[0][nt] = mfma16(ga[s][0][kc], bf, acc0[0][nt]);
                acc0[1][nt] = mfma16(ga[s][1][kc], bf, acc0[1][nt]);
            }
    }
    {   // t1 = h @ b10 (own row)
        const unsigned short* bl = wlds + 27 * 4 * 512 + lane * 8;
#pragma unroll
        for (int m = 0; m < 2; ++m) {
            const unsigned short* ar = h + (size_t)(vb + m * 16 + lrow) * 64;
#pragma unroll
            for (int kc = 0; kc < 2; ++kc) {
                const bf16x8 af = ld8(ar + kc * 32 + lkg * 8);
#pragma unroll
                for (int nt = 0; nt < 2; ++nt) {
                    const bf16x8 bf = ld8(bl + (kc * 2 + nt) * 512);
                    acc1[m][nt] = mfma16(af, bf, acc1[m][nt]);
                }
            }
        }
    }
#pragma unroll
    for (int m = 0; m < 2; ++m)
#pragma unroll
        for (int nt = 0; nt < 2; ++nt)
#pragma unroll
            for (int r = 0; r < 4; ++r) {
                const int v = vb + m * 16 + lkg * 4 + r;
                u[(size_t)v * 64 + nt * 16 + lrow] = f2b_rne(fmaxf(acc0[m][nt][r], 0.f));
                u[(size_t)v * 64 + 32 + nt * 16 + lrow] = f2b_rne(fmaxf(acc1[m][nt][r], 0.f));
            }
}

// K_B: out0 = conv27(u_lo, b01); t2 = relu(conv27(u_hi, b11)); out1 = t2 @ b12;
// hout = [out0|out1] + hres (+ xres if non-null)
__global__ __launch_bounds__(1024)
void kernel_B(const unsigned short* __restrict__ u,
              const int* __restrict__ nbr,
              const unsigned short* __restrict__ b01f,
              const unsigned short* __restrict__ b11f,
              const unsigned short* __restrict__ b12f,
              const unsigned short* __restrict__ hres,
              const unsigned short* __restrict__ xres,
              unsigned short* __restrict__ hout)
{
    __shared__ unsigned short wlds[110 * 512];
    __shared__ unsigned short t2lds[16][512];
    const int tid = threadIdx.x;
    const int lane = tid & 63, wave = tid >> 6;
    const int lrow = lane & 15, lkg = lane >> 4;
    const int vb = blockIdx.x * 512 + wave * 32;

    constexpr int ID = 6;
    constexpr int GS = 3;

    const int* nrow0 = nbr + (size_t)(vb + lrow) * 27;
    const int* nrow1 = nbr + (size_t)(vb + 16 + lrow) * 27;

    int i0[ID], i1[ID];
    bf16x8 ga[GS][2][2];    // [slot][m][half]

#pragma unroll
    for (int t = 0; t < ID; ++t) { i0[t] = nrow0[t]; i1[t] = nrow1[t]; }
#pragma unroll
    for (int t = 0; t < 2; ++t) {
        const unsigned short* a0 = u + (size_t)i0[t] * 64 + lkg * 8;
        const unsigned short* a1 = u + (size_t)i1[t] * 64 + lkg * 8;
        ga[t][0][0] = ld8(a0); ga[t][0][1] = ld8(a0 + 32);
        ga[t][1][0] = ld8(a1); ga[t][1][1] = ld8(a1 + 32);
    }

    stage16(b01f, wlds, 54 * 64, tid, 1024);
    stage16(b11f, wlds + 54 * 512, 54 * 64, tid, 1024);
    stage16(b12f, wlds + 108 * 512, 2 * 64, tid, 1024);

    const f32x4 FZ = {0.f, 0.f, 0.f, 0.f};
    f32x4 acc0[2][2], acc1[2][2];
#pragma unroll
    for (int m = 0; m < 2; ++m)
#pragma unroll
        for (int nt = 0; nt < 2; ++nt) { acc0[m][nt] = FZ; acc1[m][nt] = FZ; }

    __syncthreads();

#pragma unroll
    for (int t = 0; t < 27; ++t) {
        if (t + ID < 27) {
            i0[t % ID] = nrow0[t + ID];
            i1[t % ID] = nrow1[t + ID];
        }
        if (t + 2 < 27) {
            const int u2 = t + 2, s = u2 % GS;
            const unsigned short* a0 = u + (size_t)i0[u2 % ID] * 64 + lkg * 8;
            const unsigned short* a1 = u + (size_t)i1[u2 % ID] * 64 + lkg * 8;
            ga[s][0][0] = ld8(a0); ga[s][0][1] = ld8(a0 + 32);
            ga[s][1][0] = ld8(a1); ga[s][1][1] = ld8(a1 + 32);
        }
        const unsigned short* bl = wlds + lane * 8;
        const int s = t % GS;
#pragma unroll
        for (int nt = 0; nt < 2; ++nt) {
            const bf16x8 w01 = ld8(bl + (t * 2 + nt) * 512);
            const bf16x8 w11 = ld8(bl + (54 + t * 2 + nt) * 512);
            acc0[0][nt] = mfma16(ga[s][0][0], w01, acc0[0][nt]);
            acc0[1][nt] = mfma16(ga[s][1][0], w01, acc0[1][nt]);
            acc1[0][nt] = mfma16(ga[s][0][1], w11, acc1[0][nt]);
            acc1[1][nt] = mfma16(ga[s][1][1], w11, acc1[1][nt]);
        }
    }

    // out1 = relu(acc1) @ b12 via per-wave LDS transpose (XOR granule swizzle)
    f32x4 out1[2][2];
    char* tb = reinterpret_cast<char*>(&t2lds[wave][0]);
#pragma unroll
    for (int m = 0; m < 2; ++m) {
#pragma unroll
        for (int nt = 0; nt < 2; ++nt)
#pragma unroll
            for (int r = 0; r < 4; ++r) {
                const int row = lkg * 4 + r;
                const int byte = (nt * 16 + lrow) * 2;
                const int off = row * 64 + (((byte >> 4) ^ (row & 3)) << 4) + (byte & 15);
                *reinterpret_cast<unsigned short*>(tb + off) = f2b_rne(fmaxf(acc1[m][nt][r], 0.f));
            }
        __syncthreads();
        const int roff = lrow * 64 + ((lkg ^ (lrow & 3)) << 4);
        const bf16x8 af2 = *reinterpret_cast<const bf16x8*>(tb + roff);
#pragma unroll
        for (int nt = 0; nt < 2; ++nt) {
            const bf16x8 w12 = ld8(wlds + (108 + nt) * 512 + lane * 8);
            out1[m][nt] = mfma16(af2, w12, FZ);
        }
        __syncthreads();   // protects t2lds reuse (read m before write m+1)
    }

#pragma unroll
    for (int m = 0; m < 2; ++m)
#pragma unroll
        for (int nt = 0; nt < 2; ++nt)
#pragma unroll
            for (int r = 0; r < 4; ++r) {
                const int v = vb + m * 16 + lkg * 4 + r;
                const int c0 = nt * 16 + lrow;
                const int c1 = 32 + c0;
                float r0 = acc0[m][nt][r] + b2f(hres[(size_t)v * 64 + c0]);
                float r1 = out1[m][nt][r] + b2f(hres[(size_t)v * 64 + c1]);
                if (xres) {
                    r0 += b2f(xres[(size_t)v * 64 + c0]);
                    r1 += b2f(xres[(size_t)v * 64 + c1]);
                }
                hout[(size_t)v * 64 + c0] = f2b_rne(r0);
                hout[(size_t)v * 64 + c1] = f2b_rne(r1);
            }
}

// ---------------- host ----------------

extern "C" void kernel_launch(void* const* d_in, const int* in_sizes, int n_in,
                              void* d_out, int out_size, void* d_ws, size_t ws_size,
                              hipStream_t stream)
{
    const float* feats = (const float*)d_in[0];
    const int*   nbr   = (const int*)d_in[1];
    const float* w1    = (const float*)d_in[2];
    const float* w2    = (const float*)d_in[3];
    const float* b00   = (const float*)d_in[4];
    const float* b01   = (const float*)d_in[5];
    const float* b10   = (const float*)d_in[6];
    const float* b11   = (const float*)d_in[7];
    const float* b12   = (const float*)d_in[8];

    const size_t NC = (size_t)NVOX * 64;               // 16777216 elements
    unsigned short* xbuf = (unsigned short*)d_ws;      // x = relu(conv1)
    unsigned short* hbuf = xbuf + NC;                  // residual stream h
    unsigned short* wbuf = hbuf + NC;                  // bf16 frag-order weights
    if (ws_size < (2 * NC + 562176) * sizeof(unsigned short)) return;

    // d_out (fp32, 64MB) doubles as scratch for fbuf+ubuf until the final conv overwrites it
    unsigned short* fbuf = (unsigned short*)d_out;     // feats bf16
    unsigned short* ubuf = fbuf + NC;                  // u = [t0|t1]

    const size_t OFF_W1 = 0, OFF_W2 = 110592, OFF_B00 = 221184, OFF_B01 = 387072,
                 OFF_B10 = 470016, OFF_B11 = 476160, OFF_B12 = 559104;

    f2b_kernel<<<8192, 256, 0, stream>>>(feats, fbuf);
    wconv_kernel<<<dim3(432, 1), 256, 0, stream>>>(w1, wbuf + OFF_W1, 27, 64, 64);
    wconv_kernel<<<dim3(432, 1), 256, 0, stream>>>(w2, wbuf + OFF_W2, 27, 64, 64);
    wconv_kernel<<<dim3(216, 3), 256, 0, stream>>>(b00, wbuf + OFF_B00, 27, 64, 32);
    wconv_kernel<<<dim3(108, 3), 256, 0, stream>>>(b01, wbuf + OFF_B01, 27, 32, 32);
    wconv_kernel<<<dim3(8, 3),   256, 0, stream>>>(b10, wbuf + OFF_B10, 1, 64, 32);
    wconv_kernel<<<dim3(108, 3), 256, 0, stream>>>(b11, wbuf + OFF_B11, 27, 32, 32);
    wconv_kernel<<<dim3(4, 3),   256, 0, stream>>>(b12, wbuf + OFF_B12, 1, 32, 32);

    // x = relu(conv27(feats, w1))
    conv_full_kernel<true, false><<<512, 1024, 0, stream>>>(fbuf, nbr, wbuf + OFF_W1, xbuf);

    for (int i = 0; i < 3; ++i) {
        kernel_A<<<512, 1024, 0, stream>>>(i ? hbuf : xbuf, nbr,
                                           wbuf + OFF_B00 + (size_t)i * 55296,
                                           wbuf + OFF_B10 + (size_t)i * 2048, ubuf);
        kernel_B<<<512, 1024, 0, stream>>>(ubuf, nbr,
                                           wbuf + OFF_B01 + (size_t)i * 27648,
                                           wbuf + OFF_B11 + (size_t)i * 27648,
                                           wbuf + OFF_B12 + (size_t)i * 1024,
                                           i ? hbuf : xbuf,
                                           (i == 2) ? xbuf : (const unsigned short*)nullptr,
                                           hbuf);
    }

    // final: d_out = conv27(h3 + x, w2)  (fp32 out)
    conv_full_kernel<false, true><<<512, 1024, 0, stream>>>(hbuf, nbr, wbuf + OFF_W2, d_out);
}